// Round 5
// baseline (181.344 us; speedup 1.0000x reference)
//
#include <hip/hip_runtime.h>

constexpr int NL = 256;   // lights
constexpr int HW = 256;   // H == W
constexpr int NKEY = 4096;    // (y0>>4)<<8 | morton_rank(i0)

// 8-byte value with 4-byte alignment (x-pair load)
struct __attribute__((aligned(4))) F2 { float a, b; };

struct alignas(16) Rec {
    float px, py, w0, w1, w2;
    unsigned meta;   // i0 | i1<<8 | i2<<16
    unsigned p;      // original point index
    unsigned pad;
};

// ------------- pass 0: Morton-order the lights (1 block) -------------
__global__ __launch_bounds__(256)
void k_lightorder(const float* __restrict__ lpos, unsigned* __restrict__ rank)
{
    __shared__ unsigned s[NL];
    int t = threadIdx.x;
    float x = lpos[2 * t], y = lpos[2 * t + 1];
    unsigned qx = (unsigned)fminf(fmaxf((x + 3.5f) * (255.f / 7.f), 0.f), 255.f);
    unsigned qy = (unsigned)fminf(fmaxf((y + 3.5f) * (255.f / 7.f), 0.f), 255.f);
    unsigned m = 0;
    #pragma unroll
    for (int b = 0; b < 8; ++b)
        m |= (((qx >> b) & 1u) << (2 * b)) | (((qy >> b) & 1u) << (2 * b + 1));
    s[t] = (m << 8) | (unsigned)t;       // composite: unique, deterministic
    __syncthreads();
    for (int k = 2; k <= NL; k <<= 1) {
        for (int j = k >> 1; j > 0; j >>= 1) {
            unsigned p = (unsigned)t ^ (unsigned)j;
            unsigned a = s[t], b2 = s[p];
            bool asc = ((t & k) == 0);
            bool lowHalf = ((t & j) == 0);
            unsigned keep = (lowHalf == asc) ? min(a, b2) : max(a, b2);
            __syncthreads();
            s[t] = keep;
            __syncthreads();
        }
    }
    rank[s[t] & 255u] = (unsigned)t;     // light id -> spatial rank
}

// ------------- pass 1: scan + record + bucket count -------------
__global__ __launch_bounds__(256)
void k_scan(const float* __restrict__ X,
            const float* __restrict__ lpos,
            const unsigned* __restrict__ rank,
            Rec* __restrict__ recs,
            unsigned* __restrict__ count, int B)
{
    __shared__ float2 s_lp[NL];
    for (int i = threadIdx.x; i < NL; i += 256)
        s_lp[i] = reinterpret_cast<const float2*>(lpos)[i];
    __syncthreads();

    int b = blockIdx.x * 256 + threadIdx.x;
    if (b >= B) return;

    float4 xv = reinterpret_cast<const float4*>(X)[b];
    float qx = xv.z, qy = xv.w;

    float dd0 = INFINITY, dd1 = INFINITY, dd2 = INFINITY;
    int i0 = 0, i1 = 0, i2 = 0;
    #pragma unroll 4
    for (int i = 0; i < NL; ++i) {
        float2 lp = s_lp[i];
        float dx = qx - lp.x, dy = qy - lp.y;
        float d = dx * dx + dy * dy;
        bool c0 = d < dd0, c1 = d < dd1, c2 = d < dd2;
        dd2 = c1 ? dd1 : (c2 ? d : dd2);
        i2  = c1 ? i1  : (c2 ? i : i2);
        dd1 = c0 ? dd0 : (c1 ? d : dd1);
        i1  = c0 ? i0  : (c1 ? i : i1);
        dd0 = c0 ? d   : dd0;
        i0  = c0 ? i   : i0;
    }

    // barycentric weights (branchless fallback; NaN -> fallback)
    float2 p0 = s_lp[i0], p1 = s_lp[i1], p2c = s_lp[i2];
    float v0x = p1.x - p0.x,  v0y = p1.y - p0.y;
    float v1x = p2c.x - p0.x, v1y = p2c.y - p0.y;
    float v2x = qx - p0.x,    v2y = qy - p0.y;
    float d00 = v0x * v0x + v0y * v0y;
    float d11 = v1x * v1x + v1y * v1y;
    float d01 = v0x * v1x + v0y * v1y;
    float d20 = v2x * v0x + v2y * v0y;
    float d21 = v2x * v1x + v2y * v1y;
    float denom = d00 * d11 - d01 * d01;
    float v = (d11 * d20 - d01 * d21) / denom;
    float w = (d00 * d21 - d01 * d20) / denom;
    float u = 1.0f - v - w;
    bool inside = (u >= 0.f) & (v >= 0.f) & (w >= 0.f);
    float t = fminf(fmaxf(d20 / d00, 0.f), 1.f);
    float w0 = inside ? u : (1.f - t);
    float w1 = inside ? v : t;
    float w2 = inside ? w : 0.f;

    float px = fminf(fmaxf((xv.x + 1.f) * 0.5f * (HW - 1), 0.f), (float)(HW - 1));
    float py = fminf(fmaxf((xv.y + 1.f) * 0.5f * (HW - 1), 0.f), (float)(HW - 1));
    int y0 = (int)floorf(py);

    Rec r;
    r.px = px; r.py = py; r.w0 = w0; r.w1 = w1; r.w2 = w2;
    r.meta = (unsigned)i0 | ((unsigned)i1 << 8) | ((unsigned)i2 << 16);
    r.p = (unsigned)b; r.pad = 0;
    recs[b] = r;

    unsigned key = ((unsigned)(y0 >> 4) << 8) | rank[i0];   // band-major
    atomicAdd(&count[key], 1u);
}

// ------------- pass 2: exclusive prefix over 4096 counts -------------
__global__ __launch_bounds__(1024)
void k_prefix(unsigned* __restrict__ count)
{
    __shared__ unsigned part[1024];
    int t = threadIdx.x;
    unsigned l0 = count[t * 4 + 0], l1 = count[t * 4 + 1];
    unsigned l2 = count[t * 4 + 2], l3 = count[t * 4 + 3];
    part[t] = l0 + l1 + l2 + l3;
    __syncthreads();
    for (int off = 1; off < 1024; off <<= 1) {
        unsigned nv = part[t];
        if (t >= off) nv += part[t - off];
        __syncthreads();
        part[t] = nv;
        __syncthreads();
    }
    unsigned run = (t == 0) ? 0u : part[t - 1];
    count[t * 4 + 0] = run; run += l0;
    count[t * 4 + 1] = run; run += l1;
    count[t * 4 + 2] = run; run += l2;
    count[t * 4 + 3] = run;
}

// ------------- pass 3: counting-sort scatter -------------
__global__ __launch_bounds__(256)
void k_scatter(const Rec* __restrict__ recs,
               const unsigned* __restrict__ rank,
               unsigned* __restrict__ count,
               Rec* __restrict__ sorted, int B)
{
    int b = blockIdx.x * 256 + threadIdx.x;
    if (b >= B) return;
    Rec r = recs[b];
    int y0 = (int)floorf(r.py);
    unsigned key = ((unsigned)(y0 >> 4) << 8) | rank[r.meta & 255u];
    unsigned slot = atomicAdd(&count[key], 1u);
    sorted[slot] = r;
}

// ------------- pass 4: locality-sorted gather -------------
__global__ __launch_bounds__(256, 4)
void k_gather(const Rec* __restrict__ sorted,
              const float* __restrict__ shots,
              float* __restrict__ out, int B, int nwg)
{
    int bid = blockIdx.x;
    int g = bid;
    if ((nwg & 7) == 0) {                 // XCD-chunked swizzle (bijective)
        int chunk = nwg >> 3;
        g = (bid & 7) * chunk + (bid >> 3);
    }
    int idx = g * 256 + threadIdx.x;
    if (idx >= B) return;

    Rec r = sorted[idx];
    float px = r.px, py = r.py;
    int x0 = (int)floorf(px), y0 = (int)floorf(py);
    int y1 = min(y0 + 1, HW - 1);
    float wx = px - (float)x0, wy = py - (float)y0;
    float w00 = (1.f - wy) * (1.f - wx), w01 = (1.f - wy) * wx;
    float w10 = wy * (1.f - wx),         w11 = wy * wx;
    int  xe  = min(x0, HW - 2);
    bool xhi = (x0 == HW - 1);

    unsigned m = r.meta;
    int   li[3] = { (int)(m & 255u), (int)((m >> 8) & 255u), (int)((m >> 16) & 255u) };
    float wk[3] = { r.w0, r.w1, r.w2 };

    F2 G0[9], G1[9];
    #pragma unroll
    for (int k = 0; k < 3; ++k) {
        const float* base = shots + (size_t)li[k] * (3 * HW * HW);
        #pragma unroll
        for (int c = 0; c < 3; ++c) {
            const float* p = base + c * (HW * HW) + xe;
            int j = k * 3 + c;
            G0[j] = *reinterpret_cast<const F2*>(p + y0 * HW);
            G1[j] = *reinterpret_cast<const F2*>(p + y1 * HW);
        }
    }

    float acc[3] = { 0.f, 0.f, 0.f };
    #pragma unroll
    for (int k = 0; k < 3; ++k) {
        #pragma unroll
        for (int c = 0; c < 3; ++c) {
            int j = k * 3 + c;
            float v00 = xhi ? G0[j].b : G0[j].a;
            float v10 = xhi ? G1[j].b : G1[j].a;
            acc[c] += wk[k] * (v00 * w00 + G0[j].b * w01 +
                               v10 * w10 + G1[j].b * w11);
        }
    }

    size_t p = (size_t)r.p;
    out[p * 3 + 0] = acc[0];
    out[p * 3 + 1] = acc[1];
    out[p * 3 + 2] = acc[2];
}

// ------------- fallback: fused single kernel (ws too small) -------------
__global__ __launch_bounds__(256, 4)
void lsf_fused(const float* __restrict__ X,
               const float* __restrict__ shots,
               const float* __restrict__ lpos,
               float* __restrict__ out, int B)
{
    __shared__ float2 s_lp[NL];
    for (int i = threadIdx.x; i < NL; i += 256)
        s_lp[i] = reinterpret_cast<const float2*>(lpos)[i];
    __syncthreads();

    int b = blockIdx.x * 256 + threadIdx.x;
    if (b >= B) return;
    float4 xv = reinterpret_cast<const float4*>(X)[b];
    float qx = xv.z, qy = xv.w;

    float dd0 = INFINITY, dd1 = INFINITY, dd2 = INFINITY;
    int i0 = 0, i1 = 0, i2 = 0;
    #pragma unroll 4
    for (int i = 0; i < NL; ++i) {
        float2 lp = s_lp[i];
        float dx = qx - lp.x, dy = qy - lp.y;
        float d = dx * dx + dy * dy;
        bool c0 = d < dd0, c1 = d < dd1, c2 = d < dd2;
        dd2 = c1 ? dd1 : (c2 ? d : dd2);
        i2  = c1 ? i1  : (c2 ? i : i2);
        dd1 = c0 ? dd0 : (c1 ? d : dd1);
        i1  = c0 ? i0  : (c1 ? i : i1);
        dd0 = c0 ? d   : dd0;
        i0  = c0 ? i   : i0;
    }

    float2 p0 = s_lp[i0], p1 = s_lp[i1], p2c = s_lp[i2];
    float v0x = p1.x - p0.x,  v0y = p1.y - p0.y;
    float v1x = p2c.x - p0.x, v1y = p2c.y - p0.y;
    float v2x = qx - p0.x,    v2y = qy - p0.y;
    float d00 = v0x * v0x + v0y * v0y;
    float d11 = v1x * v1x + v1y * v1y;
    float d01 = v0x * v1x + v0y * v1y;
    float d20 = v2x * v0x + v2y * v0y;
    float d21 = v2x * v1x + v2y * v1y;
    float denom = d00 * d11 - d01 * d01;
    float v = (d11 * d20 - d01 * d21) / denom;
    float w = (d00 * d21 - d01 * d20) / denom;
    float u = 1.0f - v - w;
    bool inside = (u >= 0.f) & (v >= 0.f) & (w >= 0.f);
    float t = fminf(fmaxf(d20 / d00, 0.f), 1.f);
    float w0 = inside ? u : (1.f - t);
    float w1 = inside ? v : t;
    float w2 = inside ? w : 0.f;

    float px = fminf(fmaxf((xv.x + 1.f) * 0.5f * (HW - 1), 0.f), (float)(HW - 1));
    float py = fminf(fmaxf((xv.y + 1.f) * 0.5f * (HW - 1), 0.f), (float)(HW - 1));
    int x0 = (int)floorf(px), y0 = (int)floorf(py);
    int y1 = min(y0 + 1, HW - 1);
    float wx = px - (float)x0, wy = py - (float)y0;
    float w00 = (1.f - wy) * (1.f - wx), w01 = (1.f - wy) * wx;
    float w10 = wy * (1.f - wx),         w11 = wy * wx;
    int  xe  = min(x0, HW - 2);
    bool xhi = (x0 == HW - 1);

    int   idx3[3] = { i0, i1, i2 };
    float wk3[3]  = { w0, w1, w2 };
    F2 G0[9], G1[9];
    #pragma unroll
    for (int k = 0; k < 3; ++k) {
        const float* base = shots + (size_t)idx3[k] * (3 * HW * HW);
        #pragma unroll
        for (int c = 0; c < 3; ++c) {
            const float* p = base + c * (HW * HW) + xe;
            int j = k * 3 + c;
            G0[j] = *reinterpret_cast<const F2*>(p + y0 * HW);
            G1[j] = *reinterpret_cast<const F2*>(p + y1 * HW);
        }
    }
    float acc[3] = { 0.f, 0.f, 0.f };
    #pragma unroll
    for (int k = 0; k < 3; ++k)
        #pragma unroll
        for (int c = 0; c < 3; ++c) {
            int j = k * 3 + c;
            float v00 = xhi ? G0[j].b : G0[j].a;
            float v10 = xhi ? G1[j].b : G1[j].a;
            acc[c] += wk3[k] * (v00 * w00 + G0[j].b * w01 +
                                v10 * w10 + G1[j].b * w11);
        }
    out[(size_t)b * 3 + 0] = acc[0];
    out[(size_t)b * 3 + 1] = acc[1];
    out[(size_t)b * 3 + 2] = acc[2];
}

extern "C" void kernel_launch(void* const* d_in, const int* in_sizes, int n_in,
                              void* d_out, int out_size, void* d_ws, size_t ws_size,
                              hipStream_t stream) {
    const float* X     = (const float*)d_in[0];
    const float* shots = (const float*)d_in[1];
    const float* lpos  = (const float*)d_in[2];
    float* out = (float*)d_out;
    int B = in_sizes[0] / 4;
    int nwg = (B + 255) / 256;

    size_t off_rank   = 0;
    size_t off_count  = 1024;                                      // 256*4B, pad
    size_t off_recs   = off_count + (size_t)NKEY * sizeof(unsigned);
    size_t off_sorted = off_recs + (size_t)B * sizeof(Rec);
    size_t need       = off_sorted + (size_t)B * sizeof(Rec);

    if (ws_size >= need) {
        unsigned* rank  = (unsigned*)((char*)d_ws + off_rank);
        unsigned* count = (unsigned*)((char*)d_ws + off_count);
        Rec* recs   = (Rec*)((char*)d_ws + off_recs);
        Rec* sorted = (Rec*)((char*)d_ws + off_sorted);
        hipMemsetAsync(count, 0, (size_t)NKEY * sizeof(unsigned), stream);
        k_lightorder<<<1, 256, 0, stream>>>(lpos, rank);
        k_scan<<<nwg, 256, 0, stream>>>(X, lpos, rank, recs, count, B);
        k_prefix<<<1, 1024, 0, stream>>>(count);
        k_scatter<<<nwg, 256, 0, stream>>>(recs, rank, count, sorted, B);
        k_gather<<<nwg, 256, 0, stream>>>(sorted, shots, out, B, nwg);
    } else {
        lsf_fused<<<nwg, 256, 0, stream>>>(X, shots, lpos, out, B);
    }
}

// Round 6
// 88.724 us; speedup vs baseline: 2.0439x; 2.0439x over previous
//
#include <hip/hip_runtime.h>

constexpr int NL = 256;   // lights
constexpr int HW = 256;   // H == W

// 8-byte value with 4-byte alignment (x-pair load, same 64B line ~90% of time)
struct __attribute__((aligned(4))) F2 { float a, b; };

__global__ __launch_bounds__(256)
void lsf_kernel(const float* __restrict__ X,
                const float* __restrict__ shots,
                const float* __restrict__ lpos,
                float* __restrict__ out, int B)
{
    __shared__ float2 s_lp[NL];
    for (int i = threadIdx.x; i < NL; i += 256)
        s_lp[i] = reinterpret_cast<const float2*>(lpos)[i];
    __syncthreads();

    int b = blockIdx.x * 256 + threadIdx.x;
    if (b >= B) return;

    float4 xv = reinterpret_cast<const float4*>(X)[b];
    float qx = xv.z, qy = xv.w;

    // ---- top-3 nearest lights (exact semantics, ties -> lower index) ----
    float dd0 = INFINITY, dd1 = INFINITY, dd2 = INFINITY;
    int i0 = 0, i1 = 0, i2 = 0;
    #pragma unroll 4
    for (int i = 0; i < NL; ++i) {
        float2 lp = s_lp[i];
        float dx = qx - lp.x, dy = qy - lp.y;
        float d = dx * dx + dy * dy;
        bool c0 = d < dd0, c1 = d < dd1, c2 = d < dd2;
        dd2 = c1 ? dd1 : (c2 ? d : dd2);
        i2  = c1 ? i1  : (c2 ? i : i2);
        dd1 = c0 ? dd0 : (c1 ? d : dd1);
        i1  = c0 ? i0  : (c1 ? i : i1);
        dd0 = c0 ? d   : dd0;
        i0  = c0 ? i   : i0;
    }

    // ---- barycentric weights (branchless fallback; NaN -> fallback) ----
    float2 p0 = s_lp[i0], p1 = s_lp[i1], p2c = s_lp[i2];
    float v0x = p1.x - p0.x,  v0y = p1.y - p0.y;
    float v1x = p2c.x - p0.x, v1y = p2c.y - p0.y;
    float v2x = qx - p0.x,    v2y = qy - p0.y;
    float d00 = v0x * v0x + v0y * v0y;
    float d11 = v1x * v1x + v1y * v1y;
    float d01 = v0x * v1x + v0y * v1y;
    float d20 = v2x * v0x + v2y * v0y;
    float d21 = v2x * v1x + v2y * v1y;
    float denom = d00 * d11 - d01 * d01;
    float v = (d11 * d20 - d01 * d21) / denom;
    float w = (d00 * d21 - d01 * d20) / denom;
    float u = 1.0f - v - w;
    bool inside = (u >= 0.f) & (v >= 0.f) & (w >= 0.f);
    float t = fminf(fmaxf(d20 / d00, 0.f), 1.f);
    float w0 = inside ? u : (1.f - t);
    float w1 = inside ? v : t;
    float w2 = inside ? w : 0.f;

    // ---- bilinear coords ----
    float px = fminf(fmaxf((xv.x + 1.f) * 0.5f * (HW - 1), 0.f), (float)(HW - 1));
    float py = fminf(fmaxf((xv.y + 1.f) * 0.5f * (HW - 1), 0.f), (float)(HW - 1));
    int x0 = (int)floorf(px), y0 = (int)floorf(py);
    int y1 = min(y0 + 1, HW - 1);
    float wx = px - (float)x0, wy = py - (float)y0;
    float w00 = (1.f - wy) * (1.f - wx), w01 = (1.f - wy) * wx;
    float w10 = wy * (1.f - wx),         w11 = wy * wx;
    int  xe  = min(x0, HW - 2);
    bool xhi = (x0 == HW - 1);

    // ---- gather: issue ALL loads, then hard scheduler fence ----
    int idx3[3] = { i0, i1, i2 };
    F2 G0[9], G1[9];
    #pragma unroll
    for (int k = 0; k < 3; ++k) {
        const float* base = shots + (size_t)idx3[k] * (3 * HW * HW);
        #pragma unroll
        for (int c = 0; c < 3; ++c) {
            const float* p = base + c * (HW * HW) + xe;
            int j = k * 3 + c;
            G0[j] = *reinterpret_cast<const F2*>(p + y0 * HW);
            G1[j] = *reinterpret_cast<const F2*>(p + y1 * HW);
        }
    }
    // No instruction may cross this point: all 36 loads issued (defs above),
    // all consumers below -> regalloc must keep 36 values live -> 36-deep MLP.
    __builtin_amdgcn_sched_barrier(0);

    float wk3[3] = { w0, w1, w2 };
    float acc[3] = { 0.f, 0.f, 0.f };
    #pragma unroll
    for (int k = 0; k < 3; ++k) {
        #pragma unroll
        for (int c = 0; c < 3; ++c) {
            int j = k * 3 + c;
            float v00 = xhi ? G0[j].b : G0[j].a;
            float v10 = xhi ? G1[j].b : G1[j].a;
            acc[c] += wk3[k] * (v00 * w00 + G0[j].b * w01 +
                                v10 * w10 + G1[j].b * w11);
        }
    }

    out[(size_t)b * 3 + 0] = acc[0];
    out[(size_t)b * 3 + 1] = acc[1];
    out[(size_t)b * 3 + 2] = acc[2];
}

extern "C" void kernel_launch(void* const* d_in, const int* in_sizes, int n_in,
                              void* d_out, int out_size, void* d_ws, size_t ws_size,
                              hipStream_t stream) {
    const float* X     = (const float*)d_in[0];
    const float* shots = (const float*)d_in[1];
    const float* lpos  = (const float*)d_in[2];
    float* out = (float*)d_out;
    int B = in_sizes[0] / 4;
    int grid = (B + 255) / 256;
    lsf_kernel<<<grid, 256, 0, stream>>>(X, shots, lpos, out, B);
}

// Round 7
// 84.550 us; speedup vs baseline: 2.1448x; 1.0494x over previous
//
#include <hip/hip_runtime.h>

constexpr int NL = 256;   // lights
constexpr int HW = 256;   // H == W

// 8-byte value with 4-byte alignment (x-pair load, same 64B line ~90% of time)
struct __attribute__((aligned(4))) F2 { float a, b; };

__global__ __launch_bounds__(256, 8)
void lsf_kernel(const float* __restrict__ X,
                const float* __restrict__ shots,
                const float* __restrict__ lpos,
                float* __restrict__ out, int B)
{
    __shared__ float2 s_lp[NL];
    for (int i = threadIdx.x; i < NL; i += 256)
        s_lp[i] = reinterpret_cast<const float2*>(lpos)[i];
    __syncthreads();

    int tid = blockIdx.x * 256 + threadIdx.x;
    int p   = tid >> 1;        // point index
    int h   = tid & 1;         // half: 0 -> lights [0,128) + row y0, 1 -> rest
    if (p >= B) return;

    float4 xv = reinterpret_cast<const float4*>(X)[p];
    float qx = xv.z, qy = xv.w;

    // ---- half-scan: top-3 of my 128 lights (strict <, ties -> lower idx) ----
    float dd0 = INFINITY, dd1 = INFINITY, dd2 = INFINITY;
    int i0 = 0, i1 = 0, i2 = 0;
    auto visit = [&](float d, int idx) {
        bool c0 = d < dd0, c1 = d < dd1, c2 = d < dd2;
        dd2 = c1 ? dd1 : (c2 ? d : dd2);
        i2  = c1 ? i1  : (c2 ? idx : i2);
        dd1 = c0 ? dd0 : (c1 ? d : dd1);
        i1  = c0 ? i0  : (c1 ? idx : i1);
        dd0 = c0 ? d   : dd0;
        i0  = c0 ? idx : i0;
    };
    int base = h * (NL / 2);
    #pragma unroll 4
    for (int i = base; i < base + NL / 2; ++i) {
        float2 lp = s_lp[i];
        float dx = qx - lp.x, dy = qy - lp.y;
        visit(dx * dx + dy * dy, i);
    }

    // ---- pair-merge: exchange triples, insert high-half into low-half ----
    float ad0 = __shfl_xor(dd0, 1), ad1 = __shfl_xor(dd1, 1), ad2 = __shfl_xor(dd2, 1);
    int   ai0 = __shfl_xor(i0, 1),  ai1 = __shfl_xor(i1, 1),  ai2 = __shfl_xor(i2, 1);
    // low list = the one covering lights [0,128)  (owned by h==0)
    float hd0 = h ? dd0 : ad0, hd1 = h ? dd1 : ad1, hd2 = h ? dd2 : ad2;
    int   hi0 = h ? i0  : ai0, hi1 = h ? i1  : ai1, hi2 = h ? i2  : ai2;
    float ld0 = h ? ad0 : dd0, ld1 = h ? ad1 : dd1, ld2 = h ? ad2 : dd2;
    int   li0 = h ? ai0 : i0,  li1 = h ? ai1 : i1,  li2 = h ? ai2 : i2;
    dd0 = ld0; dd1 = ld1; dd2 = ld2; i0 = li0; i1 = li1; i2 = li2;
    visit(hd0, hi0);   // strict <  => equal dist keeps low-half (lower index)
    visit(hd1, hi1);
    visit(hd2, hi2);

    // ---- barycentric weights (branchless fallback; NaN -> fallback) ----
    float2 p0 = s_lp[i0], p1 = s_lp[i1], p2c = s_lp[i2];
    float v0x = p1.x - p0.x,  v0y = p1.y - p0.y;
    float v1x = p2c.x - p0.x, v1y = p2c.y - p0.y;
    float v2x = qx - p0.x,    v2y = qy - p0.y;
    float d00 = v0x * v0x + v0y * v0y;
    float d11 = v1x * v1x + v1y * v1y;
    float d01 = v0x * v1x + v0y * v1y;
    float d20 = v2x * v0x + v2y * v0y;
    float d21 = v2x * v1x + v2y * v1y;
    float denom = d00 * d11 - d01 * d01;
    float v = (d11 * d20 - d01 * d21) / denom;
    float w = (d00 * d21 - d01 * d20) / denom;
    float u = 1.0f - v - w;
    bool inside = (u >= 0.f) & (v >= 0.f) & (w >= 0.f);
    float t = fminf(fmaxf(d20 / d00, 0.f), 1.f);
    float w0 = inside ? u : (1.f - t);
    float w1 = inside ? v : t;
    float w2 = inside ? w : 0.f;

    // ---- bilinear coords; this thread handles one row ----
    float px = fminf(fmaxf((xv.x + 1.f) * 0.5f * (HW - 1), 0.f), (float)(HW - 1));
    float py = fminf(fmaxf((xv.y + 1.f) * 0.5f * (HW - 1), 0.f), (float)(HW - 1));
    int x0 = (int)floorf(px), y0 = (int)floorf(py);
    int y1 = min(y0 + 1, HW - 1);
    float wx = px - (float)x0, wy = py - (float)y0;
    int  xe  = min(x0, HW - 2);
    bool xhi = (x0 == HW - 1);
    int   row = h ? y1 : y0;
    float rw  = h ? wy : (1.f - wy);

    // ---- gather: 9 x-pair loads (one row), all issued, then fence ----
    int idx3[3] = { i0, i1, i2 };
    F2 G[9];
    #pragma unroll
    for (int k = 0; k < 3; ++k) {
        unsigned lo = (unsigned)(idx3[k] * 3) << 16;   // light base (elements)
        #pragma unroll
        for (int c = 0; c < 3; ++c) {
            unsigned off = lo + ((unsigned)c << 16) + (unsigned)(row * HW + xe);
            G[k * 3 + c] = *reinterpret_cast<const F2*>(shots + off);
        }
    }
    __builtin_amdgcn_sched_barrier(0);   // keep all 9 loads in flight together

    float wk3[3] = { w0, w1, w2 };
    float s0 = 0.f, s1 = 0.f, s2 = 0.f;
    #pragma unroll
    for (int k = 0; k < 3; ++k) {
        float r0 = (xhi ? G[k*3+0].b : G[k*3+0].a) * (1.f - wx) + G[k*3+0].b * wx;
        float r1 = (xhi ? G[k*3+1].b : G[k*3+1].a) * (1.f - wx) + G[k*3+1].b * wx;
        float r2 = (xhi ? G[k*3+2].b : G[k*3+2].a) * (1.f - wx) + G[k*3+2].b * wx;
        s0 += wk3[k] * r0;
        s1 += wk3[k] * r1;
        s2 += wk3[k] * r2;
    }
    s0 *= rw; s1 *= rw; s2 *= rw;

    // ---- pair-combine rows, even lane writes ----
    float t0 = s0 + __shfl_xor(s0, 1);
    float t1 = s1 + __shfl_xor(s1, 1);
    float t2 = s2 + __shfl_xor(s2, 1);
    if (h == 0) {
        out[(size_t)p * 3 + 0] = t0;
        out[(size_t)p * 3 + 1] = t1;
        out[(size_t)p * 3 + 2] = t2;
    }
}

extern "C" void kernel_launch(void* const* d_in, const int* in_sizes, int n_in,
                              void* d_out, int out_size, void* d_ws, size_t ws_size,
                              hipStream_t stream) {
    const float* X     = (const float*)d_in[0];
    const float* shots = (const float*)d_in[1];
    const float* lpos  = (const float*)d_in[2];
    float* out = (float*)d_out;
    int B = in_sizes[0] / 4;
    long long T = 2LL * B;                 // 2 threads per point
    int grid = (int)((T + 255) / 256);
    lsf_kernel<<<grid, 256, 0, stream>>>(X, shots, lpos, out, B);
}